// Round 10
// baseline (653.301 us; speedup 1.0000x reference)
//
#include <hip/hip_runtime.h>
#include <hip/hip_bf16.h>

// N=4, C=256, H=W=64 -> HW=4096, E=128, 3E=384.
// qkv flat [n][o][hw] IS [n][p][384]: q=p*384+0..127, k=+128, v=+256.
// attn flat [n][i*128+d] reinterpreted as [n][e][hw] by oproj phase (raw reshape).
// Column softmax (over i): scores s=q.k/64, |s|<~1.2 -> direct sum-exp (no max).
// R18: R17's fused 5-phase kernel, but grid.sync() -> MANUAL barrier with explicit
//      agent-scope fences. R17 failed NON-DETERMINISTICALLY (absmax 0.155 one run,
//      468 another) = cross-XCD stale reads: cg grid.sync synced execution but not
//      memory (per-XCD L2 not coherent; plain stores stayed dirty in writer's L2).
//      Fix: __threadfence() (agent fence: waitcnt + buffer_wbl2/inv on gfx950) on
//      BOTH sides of a counter barrier; every block's thread0 is on a distinct
//      CU-resident block so every CU runs the invalidate. Normal launch (no coop —
//      also removes coop-under-graph-capture unknown). Grid 512 = 2/CU x 256 CU,
//      co-residency guaranteed by LDS (2x71680 <= 160K) + launch_bounds(256,2)
//      -> spin barrier cannot deadlock. Counter in ws, zeroed per replay by a
//      captured hipMemsetAsync; monotone targets 512/1024/1536/2048.

typedef short bfrag __attribute__((ext_vector_type(8)));   // 8 bf16 (4 VGPRs)
typedef float ffrag __attribute__((ext_vector_type(4)));   // 4 fp32 acc
typedef unsigned short us4 __attribute__((ext_vector_type(4)));
#define MFMA(a,b,c) __builtin_amdgcn_mfma_f32_16x16x32_bf16((a),(b),(c),0,0,0)

__device__ __forceinline__ unsigned short f2bf(float f){
  union { float f; unsigned u; } v; v.f = f;
  unsigned r = v.u + 0x7fffu + ((v.u >> 16) & 1u);   // RNE
  return (unsigned short)(r >> 16);
}
__device__ __forceinline__ float bf2f(unsigned short h){
  union { unsigned u; float f; } v; v.u = ((unsigned)h) << 16; return v.f;
}
__device__ __forceinline__ unsigned bfpack(float a, float b){
  return (unsigned)f2bf(a) | ((unsigned)f2bf(b) << 16);
}

// Manual grid barrier. Release: all threads fence (drain stores + L2 writeback),
// thread0 arrives via device-scope atomic, spins until all 512 arrived.
// Acquire: all threads fence (invalidate L1/L2) so subsequent plain loads are fresh.
__device__ __forceinline__ void grid_barrier(unsigned* bar, unsigned target){
  __syncthreads();
  __threadfence();
  if (threadIdx.x == 0){
    atomicAdd(bar, 1u);
    while (__hip_atomic_load(bar, __ATOMIC_RELAXED, __HIP_MEMORY_SCOPE_AGENT) < target)
      __builtin_amdgcn_s_sleep(2);
  }
  __syncthreads();
  __threadfence();
}

__global__ __launch_bounds__(256, 2) void k_fused(
    const float* __restrict__ x,  const float* __restrict__ Wq, const float* __restrict__ bq,
    const float* __restrict__ Wo, const float* __restrict__ bo,
    unsigned short* __restrict__ qkv, unsigned short* __restrict__ vtg_all,
    float* __restrict__ zp, unsigned short* __restrict__ part, float* __restrict__ y,
    unsigned* __restrict__ bar)
{
  __shared__ __align__(16) char smem[71680];     // overlay: max over phases
  const int bid = blockIdx.x;
  const int t = threadIdx.x, w = t>>6, lane = t&63, lr = lane&15, q4 = lane>>4;
  constexpr int LD = 136;
  const float inv64 = 0.015625f;

  // ================= Phase 1: QKV projection (768 items over 512 blocks) =================
  {
    unsigned short* As = (unsigned short*)smem;          // [128][136]  34816 B
    char* BsB = smem + 34816;                            // [64] rows x 272 B, swizzled
    for (int v = bid; v < 768; v += 512){
      const int o0=(v%3)*128, h0=((v/3)&63)*64, n=v/192;
      ffrag acc[8] = {};
      for (int kh = 0; kh < 2; ++kh) {
        __syncthreads();
        #pragma unroll
        for (int r=0;r<8;++r){                       // 2048 = 128 o x 16 segs, cast from fp32
          int pi = t + 256*r; int o = pi>>4, seg = pi&15;
          const float* wsrc = Wq + (size_t)(o0+o)*256 + kh*128 + seg*8;
          float4 w0 = *(const float4*)(wsrc);
          float4 w1 = *(const float4*)(wsrc+4);
          us4 lo, hv;
          lo.x=f2bf(w0.x); lo.y=f2bf(w0.y); lo.z=f2bf(w0.z); lo.w=f2bf(w0.w);
          hv.x=f2bf(w1.x); hv.y=f2bf(w1.y); hv.z=f2bf(w1.z); hv.w=f2bf(w1.w);
          *(us4*)&As[o*LD + seg*8]     = lo;
          *(us4*)&As[o*LD + seg*8 + 4] = hv;
        }
        #pragma unroll
        for (int r=0;r<8;++r){                       // X^T staging, swizzled column writes
          int idx = t + 256*r; int cl = idx>>4, h4 = idx&15;
          float4 v4 = *(const float4*)(x + (size_t)(n*256 + kh*128 + cl)*4096 + h0 + h4*4);
          float vv[4] = {v4.x, v4.y, v4.z, v4.w};
          #pragma unroll
          for (int u=0;u<4;++u){
            int row = h4*4+u;
            *(unsigned short*)(BsB + row*272 + ((2*cl) ^ (((row>>3)&7)<<4))) = f2bf(vv[u]);
          }
        }
        __syncthreads();
        const int arow = w*16+lr;
        const int akey = ((arow>>3)&7)<<4;
        #pragma unroll
        for (int kk=0;kk<4;++kk){
          bfrag a = *(const bfrag*)(BsB + arow*272 + ((kk*64 + q4*16) ^ akey));  // A = x^T rows (hw)
          #pragma unroll
          for (int ot=0;ot<8;++ot){
            bfrag b = *(const bfrag*)&As[(ot*16+lr)*LD + kk*32 + q4*8]; // B = W rows (o)
            acc[ot] = MFMA(a,b,acc[ot]);                                // D[m=hw][n=o]
          }
        }
      }
      size_t base = (size_t)n*384*4096;
      #pragma unroll
      for (int ot=0;ot<8;++ot){
        int o  = o0 + ot*16 + lr;
        float bias = bq[o];
        int hw = h0 + w*16 + q4*4;
        us4 pk;
        pk.x = f2bf(acc[ot][0] + bias); pk.y = f2bf(acc[ot][1] + bias);
        pk.z = f2bf(acc[ot][2] + bias); pk.w = f2bf(acc[ot][3] + bias);
        *(us4*)(qkv + base + (size_t)o*4096 + hw) = pk;
      }
    }
  }
  grid_barrier(bar, 512u);

  // ================= Phase 2: column Z partials (512 blocks) =================
  {
    unsigned short (*Qs)[64*LD] = (unsigned short(*)[64*LD])smem;   // 2 x 17408 B
    const int j0 = (bid&15)*256, ic = (bid>>4)&7, n = bid>>7;
    size_t base = (size_t)n*384*4096;
    bfrag kf[4][4];
    #pragma unroll
    for (int js=0; js<4; ++js){
      const unsigned short* krow = qkv + base + (size_t)(j0 + w*64 + js*16 + lr)*384 + 128;
      #pragma unroll
      for (int kk=0;kk<4;++kk) kf[js][kk] = *(const bfrag*)(krow + kk*32 + q4*8);
    }
    const int il = t>>4, seg = t&15;
    {
      const int i0 = (ic<<9);
      #pragma unroll
      for (int r=0;r<4;++r)
        *(uint4*)&Qs[0][(il+16*r)*LD + seg*8] =
          *(const uint4*)(qkv + base + (size_t)(i0+il+16*r)*384 + seg*8);
    }
    __syncthreads();
    float Zc[16] = {};                      // [js*4 + r]
    for (int rnd=0; rnd<8; ++rnd){          // 8 x 64-i rounds (ic chunk = 512 i)
      const int cur = rnd&1;
      uint4 qr[4];
      if (rnd<7){                           // issue next round's loads first
        const int i1 = (ic<<9) + (rnd+1)*64;
        #pragma unroll
        for (int r=0;r<4;++r)
          qr[r] = *(const uint4*)(qkv + base + (size_t)(i1+il+16*r)*384 + seg*8);
      }
      const unsigned short* qs = Qs[cur];
      #pragma unroll
      for (int it=0; it<4; ++it){
        bfrag qb[4];
        #pragma unroll
        for (int kk=0;kk<4;++kk) qb[kk] = *(const bfrag*)&qs[(it*16+lr)*LD + kk*32 + q4*8];
        #pragma unroll
        for (int js=0; js<4; ++js){
          ffrag s = {};
          #pragma unroll
          for (int kk=0;kk<4;++kk) s = MFMA(kf[js][kk], qb[kk], s);   // D[m=j][n=i]
          #pragma unroll
          for (int r=0;r<4;++r) Zc[js*4+r] += __expf(s[r]*inv64);
        }
      }
      if (rnd<7){                           // sink staged writes, one barrier per round
        #pragma unroll
        for (int r=0;r<4;++r) *(uint4*)&Qs[cur^1][(il+16*r)*LD + seg*8] = qr[r];
        __syncthreads();
      }
    }
    #pragma unroll
    for (int v=0; v<16; ++v){
      float z = Zc[v];
      z += __shfl_xor(z, 1); z += __shfl_xor(z, 2);
      z += __shfl_xor(z, 4); z += __shfl_xor(z, 8);
      Zc[v] = z;
    }
    if (lr == 0){
      int jb = j0 + w*64;
      float* zrow = zp + (size_t)((n<<3)+ic)*4096;
      #pragma unroll
      for (int js=0; js<4; ++js)
        #pragma unroll
        for (int r=0;r<4;++r)
          zrow[jb + js*16 + q4*4 + r] = Zc[js*4+r];
    }
  }
  grid_barrier(bar, 1024u);

  // ================= Phase 3: V transpose + Z-merge + 1/Z fold (blocks < 256) =================
  if (bid < 256){
    unsigned short* T = (unsigned short*)smem;           // 17408 B
    float* invZ = (float*)(smem + 17408);                // 256 B
    const int p0 = (bid&63)*64, n = bid>>6;
    size_t base = (size_t)n*384*4096;
    #pragma unroll
    for (int r=0;r<4;++r){
      int pi = t + 256*r; int pl = pi>>4, seg = pi&15;
      *(uint4*)&T[pl*LD + seg*8] = *(const uint4*)(qkv + base + (size_t)(p0+pl)*384 + 256 + seg*8);
    }
    if (t < 64){                            // merge zp partials for this block's 64 j
      float Z = 0.f;
      #pragma unroll
      for (int c=0;c<8;++c) Z += zp[(size_t)((n<<3)+c)*4096 + p0 + t];
      invZ[t] = 1.0f / Z;
    }
    __syncthreads();
    unsigned* vt32 = (unsigned*)(vtg_all + (size_t)n*128*4096);
    #pragma unroll
    for (int r=0;r<16;++r){
      int pi = t + 256*r;            // 4096 = 128 d x 32 p-pairs
      int d = pi>>5, k = pi&31;
      float lo = bf2f(T[(2*k)*LD + d])   * invZ[2*k];
      float hi = bf2f(T[(2*k+1)*LD + d]) * invZ[2*k+1];
      vt32[(size_t)d*2048 + (p0>>1) + k] = bfpack(lo, hi);
    }
  }
  grid_barrier(bar, 1536u);

  // ================= Phase 4: PV pass (512 blocks; R4 body verbatim) =================
  {
    constexpr int LDK = 136, LDV = 72;
    unsigned short (*Ks)[64*LDK] = (unsigned short(*)[64*LDK])smem;            // 2 x 17408 B
    unsigned short (*Vt)[128*LDV] = (unsigned short(*)[128*LDV])(smem + 34816);// 2 x 18432 B
    const int i0 = (bid&31)*128, jh = (bid>>5)&3, n = bid>>7;
    size_t base = (size_t)n*384*4096;
    const unsigned short* vtg = vtg_all + (size_t)n*128*4096;
    bfrag qf[2][4];   // B[k=d][n=i] for 2 i-subtiles (register-resident)
    #pragma unroll
    for (int isub=0;isub<2;++isub){
      const unsigned short* qrow = qkv + base + (size_t)(i0 + w*32 + isub*16 + lr)*384;
      #pragma unroll
      for (int kk=0;kk<4;++kk) qf[isub][kk] = *(const bfrag*)(qrow + kk*32 + q4*8);
    }
    ffrag acc[8][2] = {};
    const int jl_k = t>>4, seg_k = t&15;          // K: 16 rows per r-step
    const int d_v  = t>>3, c_v  = t&7;            // V: 32 d-rows per r-step
    const int sl0 = lr + 16*((2*q4)   & 3);
    const int sl1 = lr + 16*((2*q4+1) & 3);
    {
      const int j0 = jh*1024;
      #pragma unroll
      for (int r=0;r<4;++r)
        *(uint4*)&Ks[0][(jl_k+16*r)*LDK + seg_k*8] =
          *(const uint4*)(qkv + base + (size_t)(j0 + jl_k + 16*r)*384 + 128 + seg_k*8);
      #pragma unroll
      for (int r=0;r<4;++r)
        *(uint4*)&Vt[0][(d_v+32*r)*LDV + c_v*8] =
          *(const uint4*)(vtg + (size_t)(d_v + 32*r)*4096 + j0 + c_v*8);
    }
    __syncthreads();

    for (int it=0; it<16; ++it){
      const int cur = it & 1;
      uint4 kr[4], vr[4];
      if (it < 15){
        const int jn = jh*1024 + (it+1)*64;
        #pragma unroll
        for (int r=0;r<4;++r)
          kr[r] = *(const uint4*)(qkv + base + (size_t)(jn + jl_k + 16*r)*384 + 128 + seg_k*8);
        #pragma unroll
        for (int r=0;r<4;++r)
          vr[r] = *(const uint4*)(vtg + (size_t)(d_v + 32*r)*4096 + jn + c_v*8);
      }
      unsigned pk[4][2][2];   // [jt][isub][r-half]
      #pragma unroll
      for (int jt=0;jt<4;++jt){
        bfrag kf[4];
        #pragma unroll
        for (int kk=0;kk<4;++kk) kf[kk] = *(const bfrag*)&Ks[cur][(jt*16+lr)*LDK + kk*32 + q4*8]; // A[m=j][k=d]
        #pragma unroll
        for (int isub=0;isub<2;++isub){
          ffrag s = {};
          #pragma unroll
          for (int kk=0;kk<4;++kk) s = MFMA(kf[kk], qf[isub][kk], s);   // D[m=j][n=i]
          pk[jt][isub][0] = bfpack(__expf(s[0]*inv64), __expf(s[1]*inv64));
          pk[jt][isub][1] = bfpack(__expf(s[2]*inv64), __expf(s[3]*inv64));
        }
      }
      #pragma unroll
      for (int jk=0;jk<2;++jk){
        union { bfrag b; uint4 u; } pf0, pf1;
        unsigned v0[4], v1[4];
        #pragma unroll
        for (int m=0;m<4;++m){
          const int sl = (m<2) ? sl0 : sl1;
          unsigned a0 = __shfl(pk[2*jk  ][0][m&1], sl);
          unsigned b0 = __shfl(pk[2*jk+1][0][m&1], sl);
          v0[m] = (q4 >= 2) ? b0 : a0;
          unsigned a1 = __shfl(pk[2*jk  ][1][m&1], sl);
          unsigned b1 = __shfl(pk[2*jk+1][1][m&1], sl);
          v1[m] = (q4 >= 2) ? b1 : a1;
        }
        pf0.u = make_uint4(v0[0],v0[1],v0[2],v0[3]);
        pf1.u = make_uint4(v1[0],v1[1],v1[2],v1[3]);
        #pragma unroll
        for (int dt=0;dt<8;++dt){
          bfrag af = *(const bfrag*)&Vt[cur][(dt*16+lr)*LDV + jk*32 + q4*8]; // A[m=d][k=j]
          acc[dt][0] = MFMA(af, pf0.b, acc[dt][0]);   // D[m=d][n=i]
          acc[dt][1] = MFMA(af, pf1.b, acc[dt][1]);
        }
      }
      if (it < 15){
        #pragma unroll
        for (int r=0;r<4;++r) *(uint4*)&Ks[cur^1][(jl_k+16*r)*LDK + seg_k*8] = kr[r];
        #pragma unroll
        for (int r=0;r<4;++r) *(uint4*)&Vt[cur^1][(d_v+32*r)*LDV + c_v*8] = vr[r];
        __syncthreads();
      }
    }
    unsigned short* po = part + (size_t)(jh*4+n)*524288;
    #pragma unroll
    for (int isub=0;isub<2;++isub){
      const int i = i0 + w*32 + isub*16 + lr;
      #pragma unroll
      for (int dt=0;dt<8;++dt){
        us4 pko;
        pko.x = f2bf(acc[dt][isub][0]); pko.y = f2bf(acc[dt][isub][1]);
        pko.z = f2bf(acc[dt][isub][2]); pko.w = f2bf(acc[dt][isub][3]);
        *(us4*)(po + (size_t)i*128 + dt*16 + q4*4) = pko;
      }
    }
  }
  grid_barrier(bar, 2048u);

  // ================= Phase 5: output projection (512 blocks) =================
  {
    unsigned short* As = (unsigned short*)smem;          // Wo tile [c][e]  34816 B
    char* RtB = smem + 34816;                            // attn^T [hw][e] swizzled, 17408 B
    const int c0 = (bid&1)*128, h0 = ((bid>>1)&63)*64, n = bid>>7;
    #pragma unroll
    for (int r=0;r<8;++r){                     // Wo cast+stage
      int pi = t + 256*r; int cl = pi>>4, seg = pi&15;
      const float* wsrc = Wo + (size_t)(c0+cl)*128 + seg*8;
      float4 w0 = *(const float4*)(wsrc);
      float4 w1 = *(const float4*)(wsrc+4);
      us4 lo, hv;
      lo.x=f2bf(w0.x); lo.y=f2bf(w0.y); lo.z=f2bf(w0.z); lo.w=f2bf(w0.w);
      hv.x=f2bf(w1.x); hv.y=f2bf(w1.y); hv.z=f2bf(w1.z); hv.w=f2bf(w1.w);
      *(us4*)&As[cl*LD + seg*8]     = lo;
      *(us4*)&As[cl*LD + seg*8 + 4] = hv;
    }
    #pragma unroll
    for (int r=0;r<4;++r){                     // 1024 = 128 e x 8 h-octets, uint4 loads
      int pi = t + 256*r; int e = pi>>3, h8 = pi&7;
      size_t f = (size_t)e*4096 + h0 + h8*8;
      float a[8] = {};
      #pragma unroll
      for (int s=0;s<4;++s){
        uint4 u = *(const uint4*)(part + (size_t)(s*4+n)*524288 + f);
        a[0] += bf2f((unsigned short)(u.x & 0xffffu)); a[1] += bf2f((unsigned short)(u.x >> 16));
        a[2] += bf2f((unsigned short)(u.y & 0xffffu)); a[3] += bf2f((unsigned short)(u.y >> 16));
        a[4] += bf2f((unsigned short)(u.z & 0xffffu)); a[5] += bf2f((unsigned short)(u.z >> 16));
        a[6] += bf2f((unsigned short)(u.w & 0xffffu)); a[7] += bf2f((unsigned short)(u.w >> 16));
      }
      #pragma unroll
      for (int u2=0;u2<8;++u2){
        int row = h8*8+u2;
        *(unsigned short*)(RtB + row*272 + ((2*e) ^ (((row>>3)&7)<<4))) = f2bf(a[u2]);
      }
    }
    __syncthreads();
    ffrag acc[8] = {};
    const int arow = w*16+lr;
    const int akey = ((arow>>3)&7)<<4;
    #pragma unroll
    for (int kk=0;kk<4;++kk){
      bfrag a = *(const bfrag*)(RtB + arow*272 + ((kk*64 + q4*16) ^ akey));  // A = attn^T rows (hw)
      #pragma unroll
      for (int cs=0;cs<8;++cs){
        bfrag b = *(const bfrag*)&As[(cs*16+lr)*LD + kk*32 + q4*8]; // B = Wo rows (c)
        acc[cs] = MFMA(a,b,acc[cs]);                                // D[m=hw][n=c]
      }
    }
    #pragma unroll
    for (int cs=0;cs<8;++cs){
      int c = c0 + cs*16 + lr;
      float bias = bo[c];
      float4 v4 = { acc[cs][0]+bias, acc[cs][1]+bias, acc[cs][2]+bias, acc[cs][3]+bias };
      *(float4*)(y + ((size_t)n*256 + c)*4096 + h0 + w*16 + q4*4) = v4;
    }
  }
}

extern "C" void kernel_launch(void* const* d_in, const int* in_sizes, int n_in,
                              void* d_out, int out_size, void* d_ws, size_t ws_size,
                              hipStream_t stream){
  const float* x  = (const float*)d_in[0];
  const float* Wq = (const float*)d_in[1];
  const float* bq = (const float*)d_in[2];
  const float* Wo = (const float*)d_in[3];
  const float* bo = (const float*)d_in[4];
  float* y = (float*)d_out;
  char* ws = (char*)d_ws;
  unsigned short* qkv  = (unsigned short*)(ws + 0);          // 12,582,912
  unsigned short* vtg  = (unsigned short*)(ws + 12582912);   //  4,194,304
  float* zp   = (float*)(ws + 17039360);                     //    524,288 (4n x 8ic x 4096)
  unsigned* bar = (unsigned*)(ws + 17563648);                //         64 (grid barrier)
  unsigned short* part = (unsigned short*)(ws + 17629184);   // 16,777,216 (16 bf16 slices jh*4+n)

  hipMemsetAsync(bar, 0, 64, stream);                        // re-zeroed every graph replay
  k_fused<<<dim3(512), dim3(256), 0, stream>>>(x, Wq, bq, Wo, bo, qkv, vtg, zp, part, y, bar);
}

// Round 11
// 236.871 us; speedup vs baseline: 2.7580x; 2.7580x over previous
//
#include <hip/hip_runtime.h>
#include <hip/hip_bf16.h>

// N=4, C=256, H=W=64 -> HW=4096, E=128, 3E=384.
// qkv flat [n][o][hw] IS [n][p][384]: q=p*384+0..127, k=+128, v=+256.
// attn flat [n][i*128+d] reinterpreted as [n][e][hw] by k_oproj (raw reshape).
// Column softmax (over i): scores s=q.k/64, |s|<~1.2 -> direct sum-exp (no max).
// R19: back to 5 separate kernels (R10 proved grid-barrier fusion costs ~125us/barrier
//      on non-coherent-L2 gfx950 -- kernel boundaries ARE the cheap sync).
//      Pipe rebalance per R4 accounting (LDS ~80% busy, VMEM 11%): K/V slices per
//      jh-chunk are 256KB = L2-resident with 32x cross-block reuse, so:
//      - k_attn: Ks LDS buffer DELETED; K fragments read direct from global (VMEM/L2).
//        Vt stays LDS-staged (transposed layout needs it); dbuf + reg-prefetch kept.
//        LDS 71680 -> 36864 B.
//      - k_stats: Qs staging + ALL barriers deleted; Q read direct from global.
//      k_qkv / k_vtrans / k_oproj = R8 verbatim (fused W-cast, swizzled staging).

typedef short bfrag __attribute__((ext_vector_type(8)));   // 8 bf16 (4 VGPRs)
typedef float ffrag __attribute__((ext_vector_type(4)));   // 4 fp32 acc
typedef unsigned short us4 __attribute__((ext_vector_type(4)));
#define MFMA(a,b,c) __builtin_amdgcn_mfma_f32_16x16x32_bf16((a),(b),(c),0,0,0)

__device__ __forceinline__ unsigned short f2bf(float f){
  union { float f; unsigned u; } v; v.f = f;
  unsigned r = v.u + 0x7fffu + ((v.u >> 16) & 1u);   // RNE
  return (unsigned short)(r >> 16);
}
__device__ __forceinline__ float bf2f(unsigned short h){
  union { unsigned u; float f; } v; v.u = ((unsigned)h) << 16; return v.f;
}
__device__ __forceinline__ unsigned bfpack(float a, float b){
  return (unsigned)f2bf(a) | ((unsigned)f2bf(b) << 16);
}

// ---------------- K1: QKV projection; W cast fused into As staging; Bs swizzled ----------------
__global__ __launch_bounds__(256) void k_qkv(const float* __restrict__ x, const float* __restrict__ Wq,
                                             const float* __restrict__ bq, unsigned short* __restrict__ qkv){
  constexpr int LD = 136;                              // 272 B rows
  __shared__ __align__(16) unsigned short As[128*LD];  // W tile [o 128][c-half 128]
  __shared__ __align__(16) unsigned short Bs[64*LD];   // X^T tile [hw 64][c-half], swizzled
  char* BsB = (char*)Bs;
  const int o0 = blockIdx.x*128, h0 = blockIdx.y*64, n = blockIdx.z;
  const int t = threadIdx.x, w = t>>6, lane = t&63, lr = lane&15, q4 = lane>>4;
  ffrag acc[8] = {};
  for (int kh = 0; kh < 2; ++kh) {
    __syncthreads();
    #pragma unroll
    for (int r=0;r<8;++r){                       // 2048 = 128 o x 16 segs, cast from fp32
      int pi = t + 256*r; int o = pi>>4, seg = pi&15;
      const float* wsrc = Wq + (size_t)(o0+o)*256 + kh*128 + seg*8;
      float4 w0 = *(const float4*)(wsrc);
      float4 w1 = *(const float4*)(wsrc+4);
      us4 lo, hv;
      lo.x=f2bf(w0.x); lo.y=f2bf(w0.y); lo.z=f2bf(w0.z); lo.w=f2bf(w0.w);
      hv.x=f2bf(w1.x); hv.y=f2bf(w1.y); hv.z=f2bf(w1.z); hv.w=f2bf(w1.w);
      *(us4*)&As[o*LD + seg*8]     = lo;
      *(us4*)&As[o*LD + seg*8 + 4] = hv;
    }
    #pragma unroll
    for (int r=0;r<8;++r){                       // X^T staging, swizzled column writes
      int idx = t + 256*r; int cl = idx>>4, h4 = idx&15;
      float4 v = *(const float4*)(x + (size_t)(n*256 + kh*128 + cl)*4096 + h0 + h4*4);
      float vv[4] = {v.x, v.y, v.z, v.w};
      #pragma unroll
      for (int u=0;u<4;++u){
        int row = h4*4+u;
        *(unsigned short*)(BsB + row*272 + ((2*cl) ^ (((row>>3)&7)<<4))) = f2bf(vv[u]);
      }
    }
    __syncthreads();
    const int arow = w*16+lr;
    const int akey = ((arow>>3)&7)<<4;
    #pragma unroll
    for (int kk=0;kk<4;++kk){
      bfrag a = *(const bfrag*)(BsB + arow*272 + ((kk*64 + q4*16) ^ akey));  // A = x^T rows (hw)
      #pragma unroll
      for (int ot=0;ot<8;++ot){
        bfrag b = *(const bfrag*)&As[(ot*16+lr)*LD + kk*32 + q4*8]; // B = W rows (o)
        acc[ot] = MFMA(a,b,acc[ot]);                                // D[m=hw][n=o]
      }
    }
  }
  size_t base = (size_t)n*384*4096;
  #pragma unroll
  for (int ot=0;ot<8;++ot){
    int o  = o0 + ot*16 + lr;
    float bias = bq[o];
    int hw = h0 + w*16 + q4*4;
    us4 pk;
    pk.x = f2bf(acc[ot][0] + bias); pk.y = f2bf(acc[ot][1] + bias);
    pk.z = f2bf(acc[ot][2] + bias); pk.w = f2bf(acc[ot][3] + bias);
    *(us4*)(qkv + base + (size_t)o*4096 + hw) = pk;
  }
}

// ---------------- K2: column Z partials — NO LDS, NO barriers (Q direct from L2) ----------------
__global__ __launch_bounds__(256, 2) void k_stats(const unsigned short* __restrict__ qkv,
                                                  float* __restrict__ zp){
  const int j0 = blockIdx.x*256, ic = blockIdx.y, n = blockIdx.z;
  const int t = threadIdx.x, w = t>>6, lane = t&63, lr = lane&15, q4 = lane>>4;
  size_t base = (size_t)n*384*4096;
  bfrag kf[4][4];
  #pragma unroll
  for (int js=0; js<4; ++js){
    const unsigned short* krow = qkv + base + (size_t)(j0 + w*64 + js*16 + lr)*384 + 128;
    #pragma unroll
    for (int kk=0;kk<4;++kk) kf[js][kk] = *(const bfrag*)(krow + kk*32 + q4*8);
  }
  float Zc[16] = {};                      // [js*4 + r]
  const float inv64 = 0.015625f;
  for (int rnd=0; rnd<8; ++rnd){          // 8 x 64-i rounds (ic chunk = 512 i)
    const int i0 = (ic<<9) + rnd*64;
    #pragma unroll
    for (int it=0; it<4; ++it){
      bfrag qb[4];
      const unsigned short* qrow = qkv + base + (size_t)(i0 + it*16 + lr)*384;
      #pragma unroll
      for (int kk=0;kk<4;++kk) qb[kk] = *(const bfrag*)(qrow + kk*32 + q4*8);
      #pragma unroll
      for (int js=0; js<4; ++js){
        ffrag s = {};
        #pragma unroll
        for (int kk=0;kk<4;++kk) s = MFMA(kf[js][kk], qb[kk], s);   // D[m=j][n=i]
        #pragma unroll
        for (int r=0;r<4;++r) Zc[js*4+r] += __expf(s[r]*inv64);
      }
    }
  }
  #pragma unroll
  for (int v=0; v<16; ++v){
    float z = Zc[v];
    z += __shfl_xor(z, 1); z += __shfl_xor(z, 2);
    z += __shfl_xor(z, 4); z += __shfl_xor(z, 8);
    Zc[v] = z;
  }
  if (lr == 0){
    int jb = j0 + w*64;
    float* zrow = zp + (size_t)((n<<3)+ic)*4096;
    #pragma unroll
    for (int js=0; js<4; ++js)
      #pragma unroll
      for (int r=0;r<4;++r)
        zrow[jb + js*16 + q4*4 + r] = Zc[js*4+r];
  }
}

// ---------------- K3: V transpose + Z-merge + 1/Z fold: vt[n][d][p] = v[n][p][d] / Z[p] ----------------
__global__ __launch_bounds__(256) void k_vtrans(const unsigned short* __restrict__ qkv,
                                                const float* __restrict__ zp,
                                                unsigned short* __restrict__ vt){
  constexpr int LD = 136;
  __shared__ __align__(16) unsigned short T[64*LD];
  __shared__ float invZ[64];
  const int p0 = blockIdx.x*64, n = blockIdx.y;
  const int t = threadIdx.x;
  size_t base = (size_t)n*384*4096;
  #pragma unroll
  for (int r=0;r<4;++r){
    int pi = t + 256*r; int pl = pi>>4, seg = pi&15;
    *(uint4*)&T[pl*LD + seg*8] = *(const uint4*)(qkv + base + (size_t)(p0+pl)*384 + 256 + seg*8);
  }
  if (t < 64){                            // merge zp partials for this block's 64 j
    float Z = 0.f;
    #pragma unroll
    for (int c=0;c<8;++c) Z += zp[(size_t)((n<<3)+c)*4096 + p0 + t];
    invZ[t] = 1.0f / Z;
  }
  __syncthreads();
  unsigned* vt32 = (unsigned*)(vt + (size_t)n*128*4096);
  #pragma unroll
  for (int r=0;r<16;++r){
    int pi = t + 256*r;            // 4096 = 128 d x 32 p-pairs
    int d = pi>>5, k = pi&31;
    float lo = bf2f(T[(2*k)*LD + d])   * invZ[2*k];
    float hi = bf2f(T[(2*k+1)*LD + d]) * invZ[2*k+1];
    vt32[(size_t)d*2048 + (p0>>1) + k] = bfpack(lo, hi);
  }
}

// ---------------- K4: PV pass — K direct from global (L2), Vt LDS dbuf only ----------------
__global__ __launch_bounds__(256, 2) void k_attn(const unsigned short* __restrict__ qkv,
                                                 const unsigned short* __restrict__ vtg_all,
                                                 unsigned short* __restrict__ part){
  constexpr int LDV = 72;
  __shared__ __align__(16) unsigned short Vt[2][128*LDV];   // 2 x 18432 B = 36864
  const int i0 = blockIdx.x*128, jh = blockIdx.y, n = blockIdx.z;
  const int t = threadIdx.x, w = t>>6, lane = t&63, lr = lane&15, q4 = lane>>4;
  size_t base = (size_t)n*384*4096;
  const unsigned short* vtg = vtg_all + (size_t)n*128*4096;
  bfrag qf[2][4];   // B[k=d][n=i] for 2 i-subtiles (register-resident)
  #pragma unroll
  for (int isub=0;isub<2;++isub){
    const unsigned short* qrow = qkv + base + (size_t)(i0 + w*32 + isub*16 + lr)*384;
    #pragma unroll
    for (int kk=0;kk<4;++kk) qf[isub][kk] = *(const bfrag*)(qrow + kk*32 + q4*8);
  }
  ffrag acc[8][2] = {};
  const float inv64 = 0.015625f;

  // V staging addressing (tile-invariant parts)
  const int d_v  = t>>3, c_v  = t&7;            // V: 32 d-rows per r-step
  // shuffle source lanes: q4' = (2q4 + (m>>1)) & 3 ; m<2 -> sl0, m>=2 -> sl1
  const int sl0 = lr + 16*((2*q4)   & 3);
  const int sl1 = lr + 16*((2*q4+1) & 3);

  // prologue: stage V tile 0 into buffer 0
  {
    const int j0 = jh*1024;
    #pragma unroll
    for (int r=0;r<4;++r)
      *(uint4*)&Vt[0][(d_v+32*r)*LDV + c_v*8] =
        *(const uint4*)(vtg + (size_t)(d_v + 32*r)*4096 + j0 + c_v*8);
  }
  __syncthreads();

  for (int it=0; it<16; ++it){
    const int cur = it & 1;
    const int j0 = jh*1024 + it*64;
    // (1) issue next tile's V loads FIRST (latency hides under compute)
    uint4 vr[4];
    if (it < 15){
      const int jn = j0 + 64;
      #pragma unroll
      for (int r=0;r<4;++r)
        vr[r] = *(const uint4*)(vtg + (size_t)(d_v + 32*r)*4096 + jn + c_v*8);
    }
    // (2) QK^T: K fragments DIRECT from global (L2-resident, 32x cross-block reuse)
    unsigned pk[4][2][2];   // [jt][isub][r-half]: (r0,r1),(r2,r3) bf16 pairs
    #pragma unroll
    for (int jt=0;jt<4;++jt){
      bfrag kf[4];
      const unsigned short* krow = qkv + base + (size_t)(j0 + jt*16 + lr)*384 + 128;
      #pragma unroll
      for (int kk=0;kk<4;++kk) kf[kk] = *(const bfrag*)(krow + kk*32 + q4*8);   // A[m=j][k=d]
      #pragma unroll
      for (int isub=0;isub<2;++isub){
        ffrag s = {};
        #pragma unroll
        for (int kk=0;kk<4;++kk) s = MFMA(kf[kk], qf[isub][kk], s);   // D[m=j][n=i]
        pk[jt][isub][0] = bfpack(__expf(s[0]*inv64), __expf(s[1]*inv64));
        pk[jt][isub][1] = bfpack(__expf(s[2]*inv64), __expf(s[3]*inv64));
      }
    }
    // (3) PV: redistribute P via shuffles (D rows q4*4+r -> B rows q4*8+e), then MFMA
    #pragma unroll
    for (int jk=0;jk<2;++jk){
      union { bfrag b; uint4 u; } pf0, pf1;
      unsigned v0[4], v1[4];
      #pragma unroll
      for (int m=0;m<4;++m){
        const int sl = (m<2) ? sl0 : sl1;
        unsigned a0 = __shfl(pk[2*jk  ][0][m&1], sl);
        unsigned b0 = __shfl(pk[2*jk+1][0][m&1], sl);
        v0[m] = (q4 >= 2) ? b0 : a0;
        unsigned a1 = __shfl(pk[2*jk  ][1][m&1], sl);
        unsigned b1 = __shfl(pk[2*jk+1][1][m&1], sl);
        v1[m] = (q4 >= 2) ? b1 : a1;
      }
      pf0.u = make_uint4(v0[0],v0[1],v0[2],v0[3]);
      pf1.u = make_uint4(v1[0],v1[1],v1[2],v1[3]);
      #pragma unroll
      for (int dt=0;dt<8;++dt){
        bfrag af = *(const bfrag*)&Vt[cur][(dt*16+lr)*LDV + jk*32 + q4*8]; // A[m=d][k=j]
        acc[dt][0] = MFMA(af, pf0.b, acc[dt][0]);   // D[m=d][n=i]
        acc[dt][1] = MFMA(af, pf1.b, acc[dt][1]);
      }
    }
    // (4) sink staged V into the other buffer (vmcnt drain lands here, after compute)
    if (it < 15){
      #pragma unroll
      for (int r=0;r<4;++r) *(uint4*)&Vt[cur^1][(d_v+32*r)*LDV + c_v*8] = vr[r];
      __syncthreads();
    }
  }
  unsigned short* po = part + (size_t)(jh*4+n)*524288;
  #pragma unroll
  for (int isub=0;isub<2;++isub){
    const int i = i0 + w*32 + isub*16 + lr;
    #pragma unroll
    for (int dt=0;dt<8;++dt){
      us4 pko;
      pko.x = f2bf(acc[dt][isub][0]); pko.y = f2bf(acc[dt][isub][1]);
      pko.z = f2bf(acc[dt][isub][2]); pko.w = f2bf(acc[dt][isub][3]);
      *(us4*)(po + (size_t)i*128 + dt*16 + q4*4) = pko;
    }
  }
}

// ---------------- K5: output projection; Wo cast fused into As staging; Rt swizzled ----------------
__global__ __launch_bounds__(256) void k_oproj(const unsigned short* __restrict__ part,
                                               const float* __restrict__ Wo,
                                               const float* __restrict__ bo, float* __restrict__ y){
  constexpr int LD = 136;
  __shared__ __align__(16) unsigned short As[128*LD];  // Wo tile [c][e]
  __shared__ __align__(16) unsigned short Rt[64*LD];   // attn^T [hw][e], swizzled
  char* RtB = (char*)Rt;
  const int c0 = blockIdx.x*128, h0 = blockIdx.y*64, n = blockIdx.z;
  const int t = threadIdx.x, w = t>>6, lane = t&63, lr = lane&15, q4 = lane>>4;
  #pragma unroll
  for (int r=0;r<8;++r){                     // Wo cast+stage
    int pi = t + 256*r; int cl = pi>>4, seg = pi&15;
    const float* wsrc = Wo + (size_t)(c0+cl)*128 + seg*8;
    float4 w0 = *(const float4*)(wsrc);
    float4 w1 = *(const float4*)(wsrc+4);
    us4 lo, hv;
    lo.x=f2bf(w0.x); lo.y=f2bf(w0.y); lo.z=f2bf(w0.z); lo.w=f2bf(w0.w);
    hv.x=f2bf(w1.x); hv.y=f2bf(w1.y); hv.z=f2bf(w1.z); hv.w=f2bf(w1.w);
    *(us4*)&As[cl*LD + seg*8]     = lo;
    *(us4*)&As[cl*LD + seg*8 + 4] = hv;
  }
  #pragma unroll
  for (int r=0;r<4;++r){                     // 1024 = 128 e x 8 h-octets, uint4 loads
    int pi = t + 256*r; int e = pi>>3, h8 = pi&7;
    size_t f = (size_t)e*4096 + h0 + h8*8;
    float a[8] = {};
    #pragma unroll
    for (int s=0;s<4;++s){
      uint4 u = *(const uint4*)(part + (size_t)(s*4+n)*524288 + f);
      a[0] += bf2f((unsigned short)(u.x & 0xffffu)); a[1] += bf2f((unsigned short)(u.x >> 16));
      a[2] += bf2f((unsigned short)(u.y & 0xffffu)); a[3] += bf2f((unsigned short)(u.y >> 16));
      a[4] += bf2f((unsigned short)(u.z & 0xffffu)); a[5] += bf2f((unsigned short)(u.z >> 16));
      a[6] += bf2f((unsigned short)(u.w & 0xffffu)); a[7] += bf2f((unsigned short)(u.w >> 16));
    }
    #pragma unroll
    for (int u2=0;u2<8;++u2){
      int row = h8*8+u2;
      *(unsigned short*)(RtB + row*272 + ((2*e) ^ (((row>>3)&7)<<4))) = f2bf(a[u2]);
    }
  }
  __syncthreads();
  ffrag acc[8] = {};
  const int arow = w*16+lr;
  const int akey = ((arow>>3)&7)<<4;
  #pragma unroll
  for (int kk=0;kk<4;++kk){
    bfrag a = *(const bfrag*)(RtB + arow*272 + ((kk*64 + q4*16) ^ akey));  // A = attn^T rows (hw)
    #pragma unroll
    for (int cs=0;cs<8;++cs){
      bfrag b = *(const bfrag*)&As[(cs*16+lr)*LD + kk*32 + q4*8]; // B = Wo rows (c)
      acc[cs] = MFMA(a,b,acc[cs]);                                // D[m=hw][n=c]
    }
  }
  #pragma unroll
  for (int cs=0;cs<8;++cs){
    int c = c0 + cs*16 + lr;
    float bias = bo[c];
    float4 v4 = { acc[cs][0]+bias, acc[cs][1]+bias, acc[cs][2]+bias, acc[cs][3]+bias };
    *(float4*)(y + ((size_t)n*256 + c)*4096 + h0 + w*16 + q4*4) = v4;
  }
}

extern "C" void kernel_launch(void* const* d_in, const int* in_sizes, int n_in,
                              void* d_out, int out_size, void* d_ws, size_t ws_size,
                              hipStream_t stream){
  const float* x  = (const float*)d_in[0];
  const float* Wq = (const float*)d_in[1];
  const float* bq = (const float*)d_in[2];
  const float* Wo = (const float*)d_in[3];
  const float* bo = (const float*)d_in[4];
  float* y = (float*)d_out;
  char* ws = (char*)d_ws;
  unsigned short* qkv  = (unsigned short*)(ws + 0);          // 12,582,912
  unsigned short* vtg  = (unsigned short*)(ws + 12582912);   //  4,194,304
  float* zp   = (float*)(ws + 17039360);                     //    524,288 (4n x 8ic x 4096)
  unsigned short* part = (unsigned short*)(ws + 17629184);   // 16,777,216 (16 bf16 slices jh*4+n)

  k_qkv   <<<dim3(3,64,4),  256, 0, stream>>>(x, Wq, bq, qkv);
  k_stats <<<dim3(16,8,4),  256, 0, stream>>>(qkv, zp);
  k_vtrans<<<dim3(64,4),    256, 0, stream>>>(qkv, zp, vtg);
  k_attn  <<<dim3(32,4,4),  256, 0, stream>>>(qkv, vtg, part);
  k_oproj <<<dim3(2,64,4),  256, 0, stream>>>(part, Wo, bo, y);
}